// Round 1
// baseline (576.565 us; speedup 1.0000x reference)
//
#include <hip/hip_runtime.h>

#define FSZ 5
#define CHUNK 16

// Problem constants (from reference setup_inputs)
#define B_ 2
#define C_ 64
#define H_ 256
#define W_ 256
#define HIN (H_ + FSZ - 1)   // 260
#define WIN (W_ + FSZ - 1)   // 260

__global__ __launch_bounds__(256) void dsepconv_kernel(
    const float* __restrict__ inp,
    const float* __restrict__ vertical,
    const float* __restrict__ horizontal,
    const float* __restrict__ offx,
    const float* __restrict__ offy,
    const float* __restrict__ mask,
    float* __restrict__ out)
{
    const int NCH = C_ / CHUNK;            // 4 channel chunks
    const int x = threadIdx.x;             // 0..255 == W
    int bid = blockIdx.x;
    const int cc = bid % NCH; bid /= NCH;
    const int y  = bid % H_;  bid /= H_;
    const int b  = bid;
    const int c0 = cc * CHUNK;

    const int HW = H_ * W_;
    const int plane = HIN * WIN;
    const int pix = y * W_ + x;

    const float* vert = vertical   + (size_t)(b * FSZ) * HW + pix;
    const float* horz = horizontal + (size_t)(b * FSZ) * HW + pix;
    const float* ox   = offx + (size_t)(b * FSZ * FSZ) * HW + pix;
    const float* oy   = offy + (size_t)(b * FSZ * FSZ) * HW + pix;
    const float* mk   = mask + (size_t)(b * FSZ * FSZ) * HW + pix;
    const float* inb  = inp + (size_t)(b * C_ + c0) * plane;

    float acc[CHUNK];
    #pragma unroll
    for (int c = 0; c < CHUNK; ++c) acc[c] = 0.f;

    for (int i = 0; i < FSZ; ++i) {
        const float vi = vert[i * HW];
        const float py = (float)(y + i) + oy[(i * FSZ) * HW];  // placeholder; real per-j below
        (void)py;
        for (int j = 0; j < FSZ; ++j) {
            const int k = i * FSZ + j;
            const float offy_v = oy[k * HW];
            const float offx_v = ox[k * HW];
            const float m_v    = mk[k * HW];
            const float hj     = horz[j * HW];

            const float pyf = (float)(y + i) + offy_v;
            const float pxf = (float)(x + j) + offx_v;
            const float y0f = floorf(pyf);
            const float x0f = floorf(pxf);
            const float ay = pyf - y0f;
            const float ax = pxf - x0f;

            int y0 = (int)y0f;
            int x0 = (int)x0f;
            int y1 = y0 + 1;
            int x1 = x0 + 1;
            y0 = min(max(y0, 0), HIN - 1);
            y1 = min(max(y1, 0), HIN - 1);
            x0 = min(max(x0, 0), WIN - 1);
            x1 = min(max(x1, 0), WIN - 1);

            const float w   = vi * hj * m_v;
            const float w00 = w * (1.f - ay) * (1.f - ax);
            const float w01 = w * (1.f - ay) * ax;
            const float w10 = w * ay * (1.f - ax);
            const float w11 = w * ay * ax;

            const int i00 = y0 * WIN + x0;
            const int i01 = y0 * WIN + x1;
            const int i10 = y1 * WIN + x0;
            const int i11 = y1 * WIN + x1;

            #pragma unroll
            for (int c = 0; c < CHUNK; ++c) {
                const float* p = inb + (size_t)c * plane;
                float a = acc[c];
                a = fmaf(w00, p[i00], a);
                a = fmaf(w01, p[i01], a);
                a = fmaf(w10, p[i10], a);
                a = fmaf(w11, p[i11], a);
                acc[c] = a;
            }
        }
    }

    float* outp = out + (size_t)(b * C_ + c0) * HW + pix;
    #pragma unroll
    for (int c = 0; c < CHUNK; ++c)
        outp[(size_t)c * HW] = acc[c];
}

extern "C" void kernel_launch(void* const* d_in, const int* in_sizes, int n_in,
                              void* d_out, int out_size, void* d_ws, size_t ws_size,
                              hipStream_t stream) {
    const float* inp        = (const float*)d_in[0];
    const float* vertical   = (const float*)d_in[1];
    const float* horizontal = (const float*)d_in[2];
    const float* offset_x   = (const float*)d_in[3];
    const float* offset_y   = (const float*)d_in[4];
    const float* mask       = (const float*)d_in[5];
    float* out              = (float*)d_out;

    const int NCH = C_ / CHUNK;
    dim3 grid(B_ * H_ * NCH);
    dim3 block(W_);
    dsepconv_kernel<<<grid, block, 0, stream>>>(
        inp, vertical, horizontal, offset_x, offset_y, mask, out);
}